// Round 19
// baseline (96.124 us; speedup 1.0000x reference)
//
#include <hip/hip_runtime.h>
#include <hip/hip_bf16.h>
#include <hip/hip_fp8.h>
#include <math.h>

#define BATCH 4096
#define NROWS 8192
#define DIM 256
#define NP 64                         // 128-row panels
#define NBLK (NP * (NP + 1) / 2)      // 2080 upper-triangle tiles
#define NPIECE (2 * NP)               // 128 denominator pieces per row

// zn scale c with c^2 = 2*log2(e): sim_scaled = c^2*cos = 2*log2e*cos,
// so exp2(sim_scaled) = e^{2 cos} directly. (e4m3 is a float format ->
// relative precision is scale-invariant.)
#define ZN_SCALE 1.698643600577466f   // sqrt(2.8853900817779268)
#define LN2F 0.6931471805599453f

typedef __attribute__((ext_vector_type(4))) float f32x4;

#if defined(__has_builtin)
#if __has_builtin(__builtin_amdgcn_exp2f)
#define EXP2F(x) __builtin_amdgcn_exp2f(x)
#endif
#endif
#ifndef EXP2F
#define EXP2F(x) __expf(LN2F * (x))
#endif

static __device__ __forceinline__ unsigned char f2fp8(float x) {
    __hip_fp8_e4m3 h(x);              // OCP e4m3fn (gfx950)
    return *reinterpret_cast<unsigned char*>(&h);
}

// ---------------------------------------------------------------------------
// Kernel A: concat + L2-normalize + scale -> fp8-e4m3 fragment-packed (pk8)
// ONLY (zn eliminated). Also: inv[wid] (ZN_SCALE-folded reciprocal norm),
// rawdot[wid] = fp32 dot(z_i[wid], z_j[wid]) for wid < BATCH (positive pair),
// and zeroes the fused-reduction accumulator/counter (safe: kernel boundary
// orders this before rowloss_final each launch, incl. graph replays).
// pk8 granule = one (16-row x 32-k) fp8 fragment = 512 B; a 128-row panel
// is 32 KB contiguous (R12/R16-proven layout).
// ---------------------------------------------------------------------------
__global__ void normalize_kernel(const float* __restrict__ z_i,
                                 const float* __restrict__ z_j,
                                 unsigned char* __restrict__ pk8,
                                 float* __restrict__ inv_arr,
                                 float* __restrict__ rawdot,
                                 double* __restrict__ acc,
                                 int* __restrict__ counter) {
    if (blockIdx.x == 0 && threadIdx.x == 0) { *acc = 0.0; *counter = 0; }
    int wid  = (blockIdx.x * blockDim.x + threadIdx.x) >> 6;   // row
    int lane = threadIdx.x & 63;
    if (wid >= NROWS) return;
    const float* src = (wid < BATCH) ? (z_i + (size_t)wid * DIM)
                                     : (z_j + (size_t)(wid - BATCH) * DIM);
    float4 v = reinterpret_cast<const float4*>(src)[lane];
    float ss = v.x * v.x + v.y * v.y + v.z * v.z + v.w * v.w;
#pragma unroll
    for (int m = 1; m < 64; m <<= 1) ss += __shfl_xor(ss, m);
    float inv = ZN_SCALE / fmaxf(sqrtf(ss), 1e-8f);
    if (lane == 0) inv_arr[wid] = inv;
    uchar4 o8;
    o8.x = f2fp8(v.x * inv);
    o8.y = f2fp8(v.y * inv);
    o8.z = f2fp8(v.z * inv);
    o8.w = f2fp8(v.w * inv);
    size_t off8 = ((size_t)(wid >> 4) * 8 + (lane >> 3)) * 512
                + (size_t)(((lane & 7) >> 1) * 16 + (wid & 15)) * 8
                + (size_t)(lane & 1) * 4;
    *reinterpret_cast<uchar4*>(pk8 + off8) = o8;
    if (wid < BATCH) {                   // positive-pair raw dot (fp32)
        float4 w = reinterpret_cast<const float4*>(z_j + (size_t)wid * DIM)[lane];
        float d = v.x * w.x + v.y * w.y + v.z * w.z + v.w * w.w;
#pragma unroll
        for (int m = 1; m < 64; m <<= 1) d += __shfl_xor(d, m);
        if (lane == 0) rawdot[wid] = d;
    }
}

// ---------------------------------------------------------------------------
// Kernel B (R16 verbatim, best measured): symmetric fused sim-GEMM +
// sum-of-exp — fp8, A-in-registers (full K, 64 VGPR), B-in-LDS (staged ONCE
// per tile), ONE barrier per tile.
// Grid 2080 = upper-triangle (p,q) 128x128 tiles, XCD swizzle 8x260
// (bijective). Block = 4 waves (2x2); wave = 64x64 quadrant.
// K-loop: 8 slices of {4x ds_read_b64 + 16 MFMA}; no barriers, no vmcnt.
// Piece scheme (R12-proven, each slot written exactly once):
//   row pieces: part[q*2+wc][rows of panel p]   (all tiles)
//   col pieces: part[p*2+wr][cols of panel q]   (p!=q, symmetry)
// Row r (panel pr) coverage: ids [2pr,128) row + ids [0,2pr) col = all 128.
// ---------------------------------------------------------------------------
typedef const __attribute__((address_space(1))) unsigned int g_u32;
typedef __attribute__((address_space(3))) unsigned int l_u32;

__device__ __forceinline__ void unrank_tile(int t, int& p, int& q) {
    int pp = (int)((129.0f - sqrtf(16641.0f - 8.0f * (float)t)) * 0.5f);
    pp = pp < 0 ? 0 : (pp > 63 ? 63 : pp);
    while (pp > 0 && t < pp * (129 - pp) / 2) --pp;
    while (pp < 63 && t >= (pp + 1) * (128 - pp) / 2) ++pp;
    p = pp;
    q = pp + (t - pp * (129 - pp) / 2);
}

__global__ __launch_bounds__(256, 3)
void simloss_kernel(const unsigned char* __restrict__ pk8,
                    float* __restrict__ part /* [NPIECE][NROWS] */) {
    __shared__ __attribute__((aligned(16))) unsigned char ldsB[32768];
    int wave = threadIdx.x >> 6;
    int lane = threadIdx.x & 63;
    int lr = lane & 15;                  // fragment col
    int lk = lane >> 4;                  // fragment row group
    int wr = wave >> 1, wc = wave & 1;
    // XCD-contiguous bijective swizzle: 2080 = 8 x 260
    int bt = (int)blockIdx.x;
    int t = (bt & 7) * 260 + (bt >> 3);
    int p, q;
    unrank_tile(t, p, q);

    const char* pkb = (const char*)pk8;

    // --- stage B panel q: contiguous 32 KB, 8 chunks of 1 KB per wave ---
#pragma unroll
    for (int i = 0; i < 8; ++i) {
        int chunk = wave * 8 + i;        // 0..31
        const char* src = pkb + (size_t)q * 32768 + (size_t)chunk * 1024
                        + (size_t)lane * 16;
        char* dst = (char*)ldsB + chunk * 1024;
        __builtin_amdgcn_global_load_lds((g_u32*)src, (l_u32*)dst, 16, 0, 0);
    }

    // --- A fragments into registers: 4 row-tiles x 8 slices (64 VGPR) ---
    const char* Abase = pkb + (size_t)(p * 8 + wr * 4) * 4096 + (size_t)lane * 8;
    long long Ar[4][8];
#pragma unroll
    for (int m = 0; m < 4; ++m)
#pragma unroll
        for (int s = 0; s < 8; ++s)
            Ar[m][s] = *(const long long*)(Abase + m * 4096 + s * 512);

    f32x4 acc[4][4];
#pragma unroll
    for (int m = 0; m < 4; ++m)
#pragma unroll
        for (int n = 0; n < 4; ++n) acc[m][n] = (f32x4){0.f, 0.f, 0.f, 0.f};

    __syncthreads();                     // waits vmcnt(0) + lgkmcnt(0)

    // --- K-loop: pure LDS reads + MFMA, no barriers ---
    const char* Bb = (const char*)ldsB + (size_t)(wc * 4) * 4096
                   + (size_t)lane * 8;
#pragma unroll
    for (int s = 0; s < 8; ++s) {
        long long Bf[4];
#pragma unroll
        for (int n = 0; n < 4; ++n)
            Bf[n] = *(const long long*)(Bb + n * 4096 + s * 512);
#pragma unroll
        for (int m = 0; m < 4; ++m)
#pragma unroll
            for (int n = 0; n < 4; ++n)
                acc[m][n] = __builtin_amdgcn_mfma_f32_16x16x32_fp8_fp8(
                    Ar[m][s], Bf[n], acc[m][n], 0, 0, 0);
    }

    // ---- epilogue (R12 verbatim): exp2, diag-zero, row + col sums ----
    int R0 = p * 128 + wr * 64;
    int C0 = q * 128 + wc * 64;
    float dacc[4][4];
#pragma unroll
    for (int m = 0; m < 4; ++m)
#pragma unroll
        for (int j = 0; j < 4; ++j) dacc[m][j] = 0.f;
    float cacc[4] = {0.f, 0.f, 0.f, 0.f};

#pragma unroll
    for (int m = 0; m < 4; ++m) {
        int gr = R0 + m * 16;
#pragma unroll
        for (int n = 0; n < 4; ++n) {
            int gc = C0 + n * 16;
            bool diagf = (gr == gc);      // uniform per fragment
            float cs_ = 0.f;
#pragma unroll
            for (int j = 0; j < 4; ++j) {
                float e = EXP2F(acc[m][n][j]);
                if (diagf && lr == lk * 4 + j) e = 0.0f;
                dacc[m][j] += e;
                cs_ += e;
            }
            cacc[n] += cs_;
        }
    }

    // row pieces: reduce over 16 col-lanes (lr); lanes lr==0 write (nt)
#pragma unroll
    for (int m = 0; m < 4; ++m)
#pragma unroll
        for (int j = 0; j < 4; ++j) {
            float v = dacc[m][j];
            v += __shfl_xor(v, 1);
            v += __shfl_xor(v, 2);
            v += __shfl_xor(v, 4);
            v += __shfl_xor(v, 8);
            if (lr == 0)
                __builtin_nontemporal_store(v,
                    &part[(size_t)(q * 2 + wc) * NROWS + R0 + m * 16 + lk * 4 + j]);
        }
    // col pieces: reduce over the 4 lk groups; lanes lk==0 (0..15) write (nt)
    if (p != q) {
#pragma unroll
        for (int n = 0; n < 4; ++n) {
            float c = cacc[n];
            c += __shfl_xor(c, 16);
            c += __shfl_xor(c, 32);
            if (lk == 0)
                __builtin_nontemporal_store(c,
                    &part[(size_t)(p * 2 + wr) * NROWS + C0 + n * 16 + lr]);
        }
    }
}

// ---------------------------------------------------------------------------
// Kernel C: fused per-row loss + global reduction (last-block finisher).
// One row per wave: den = sum of 128 pieces (lane gathers 2, shfl-reduce);
// loss = log(den) - rawdot*inv[r]*inv[r^B]*ln2. Block partial -> double
// atomicAdd; counter; block seeing counter==grid-1 writes out[0].
// ---------------------------------------------------------------------------
__global__ void rowloss_final_kernel(const float* __restrict__ part,
                                     const float* __restrict__ inv_arr,
                                     const float* __restrict__ rawdot,
                                     double* __restrict__ acc,
                                     int* __restrict__ counter,
                                     float* __restrict__ out) {
    int wave = threadIdx.x >> 6;
    int lane = threadIdx.x & 63;
    int r = blockIdx.x * 4 + wave;
    float den = part[(size_t)lane * NROWS + r]
              + part[(size_t)(lane + 64) * NROWS + r];
#pragma unroll
    for (int m = 1; m < 64; m <<= 1) den += __shfl_xor(den, m);
    __shared__ float red[4];
    if (lane == 0) {
        float pdot = rawdot[r & (BATCH - 1)] * inv_arr[r] * inv_arr[r ^ BATCH];
        red[wave] = logf(den) - pdot * LN2F;
    }
    __syncthreads();
    if (threadIdx.x == 0) {
        float s = red[0] + red[1] + red[2] + red[3];
        atomicAdd(acc, (double)s);
        __threadfence();
        int old = atomicAdd(counter, 1);
        if (old == (int)gridDim.x - 1) {
            double a = *(volatile double*)acc;
            out[0] = (float)(a / (double)NROWS);
        }
    }
}

// ---------------------------------------------------------------------------
extern "C" void kernel_launch(void* const* d_in, const int* in_sizes, int n_in,
                              void* d_out, int out_size, void* d_ws, size_t ws_size,
                              hipStream_t stream) {
    const float* z_i = (const float*)d_in[0];
    const float* z_j = (const float*)d_in[1];
    float* out = (float*)d_out;
    char* ws = (char*)d_ws;

    unsigned char* pk8 = (unsigned char*)ws;                               // 2 MB
    float* part   = (float*)(ws + (size_t)NROWS * DIM);                    // 4 MB
    float* inv_a  = (float*)(ws + (size_t)NROWS * DIM
                                + (size_t)NPIECE * NROWS * 4);             // 32 KB
    float* rawdot = inv_a + NROWS;                                         // 16 KB
    double* acc   = (double*)(rawdot + BATCH);                             // 8 B
    int* counter  = (int*)(acc + 1);                                       // 4 B

    normalize_kernel<<<NROWS / 4, 256, 0, stream>>>(z_i, z_j, pk8, inv_a,
                                                    rawdot, acc, counter);
    simloss_kernel<<<NBLK, 256, 0, stream>>>(pk8, part);
    rowloss_final_kernel<<<NROWS / 4, 256, 0, stream>>>(part, inv_a, rawdot,
                                                        acc, counter, out);
}

// Round 20
// 44.655 us; speedup vs baseline: 2.1526x; 2.1526x over previous
//
#include <hip/hip_runtime.h>
#include <hip/hip_bf16.h>
#include <hip/hip_fp8.h>
#include <math.h>

#define BATCH 4096
#define NROWS 8192
#define DIM 256
#define NP 64                         // 128-row panels
#define NBLK (NP * (NP + 1) / 2)      // 2080 upper-triangle tiles
#define NPIECE (2 * NP)               // 128 denominator pieces per row

// zn scale c with c^2 = 2*log2(e): sim_scaled = c^2*cos = 2*log2e*cos,
// so exp2(sim_scaled) = e^{2 cos} directly. (e4m3 is a float format ->
// relative precision is scale-invariant.)
#define ZN_SCALE 1.698643600577466f   // sqrt(2.8853900817779268)
#define LN2F 0.6931471805599453f

typedef __attribute__((ext_vector_type(4))) float f32x4;

#if defined(__has_builtin)
#if __has_builtin(__builtin_amdgcn_exp2f)
#define EXP2F(x) __builtin_amdgcn_exp2f(x)
#endif
#endif
#ifndef EXP2F
#define EXP2F(x) __expf(LN2F * (x))
#endif

static __device__ __forceinline__ unsigned char f2fp8(float x) {
    __hip_fp8_e4m3 h(x);              // OCP e4m3fn (gfx950)
    return *reinterpret_cast<unsigned char*>(&h);
}

// ---------------------------------------------------------------------------
// Kernel A (R19-proven): concat + L2-normalize + scale -> fp8-e4m3
// fragment-packed (pk8). Also inv[wid] (ZN_SCALE-folded reciprocal norm) and
// rawdot[wid] = fp32 dot(z_i[wid], z_j[wid]) for wid < BATCH.
// pk8 granule = one (16-row x 32-k) fp8 fragment = 512 B; a 128-row panel
// is 32 KB contiguous (R12/R16-proven layout).
// ---------------------------------------------------------------------------
__global__ void normalize_kernel(const float* __restrict__ z_i,
                                 const float* __restrict__ z_j,
                                 unsigned char* __restrict__ pk8,
                                 float* __restrict__ inv_arr,
                                 float* __restrict__ rawdot) {
    int wid  = (blockIdx.x * blockDim.x + threadIdx.x) >> 6;   // row
    int lane = threadIdx.x & 63;
    if (wid >= NROWS) return;
    const float* src = (wid < BATCH) ? (z_i + (size_t)wid * DIM)
                                     : (z_j + (size_t)(wid - BATCH) * DIM);
    float4 v = reinterpret_cast<const float4*>(src)[lane];
    float ss = v.x * v.x + v.y * v.y + v.z * v.z + v.w * v.w;
#pragma unroll
    for (int m = 1; m < 64; m <<= 1) ss += __shfl_xor(ss, m);
    float inv = ZN_SCALE / fmaxf(sqrtf(ss), 1e-8f);
    if (lane == 0) inv_arr[wid] = inv;
    uchar4 o8;
    o8.x = f2fp8(v.x * inv);
    o8.y = f2fp8(v.y * inv);
    o8.z = f2fp8(v.z * inv);
    o8.w = f2fp8(v.w * inv);
    size_t off8 = ((size_t)(wid >> 4) * 8 + (lane >> 3)) * 512
                + (size_t)(((lane & 7) >> 1) * 16 + (wid & 15)) * 8
                + (size_t)(lane & 1) * 4;
    *reinterpret_cast<uchar4*>(pk8 + off8) = o8;
    if (wid < BATCH) {                   // positive-pair raw dot (fp32)
        float4 w = reinterpret_cast<const float4*>(z_j + (size_t)wid * DIM)[lane];
        float d = v.x * w.x + v.y * w.y + v.z * w.z + v.w * w.w;
#pragma unroll
        for (int m = 1; m < 64; m <<= 1) d += __shfl_xor(d, m);
        if (lane == 0) rawdot[wid] = d;
    }
}

// ---------------------------------------------------------------------------
// Kernel B (R16 verbatim, best measured): symmetric fused sim-GEMM +
// sum-of-exp — fp8, A-in-registers (full K, 64 VGPR), B-in-LDS (staged ONCE
// per tile), ONE barrier per tile.
// Grid 2080 = upper-triangle (p,q) 128x128 tiles, XCD swizzle 8x260
// (bijective). Block = 4 waves (2x2); wave = 64x64 quadrant.
// K-loop: 8 slices of {4x ds_read_b64 + 16 MFMA}; no barriers, no vmcnt.
// Piece scheme (R12-proven, each slot written exactly once):
//   row pieces: part[q*2+wc][rows of panel p]   (all tiles)
//   col pieces: part[p*2+wr][cols of panel q]   (p!=q, symmetry)
// Row r (panel pr) coverage: ids [2pr,128) row + ids [0,2pr) col = all 128.
// ---------------------------------------------------------------------------
typedef const __attribute__((address_space(1))) unsigned int g_u32;
typedef __attribute__((address_space(3))) unsigned int l_u32;

__device__ __forceinline__ void unrank_tile(int t, int& p, int& q) {
    int pp = (int)((129.0f - sqrtf(16641.0f - 8.0f * (float)t)) * 0.5f);
    pp = pp < 0 ? 0 : (pp > 63 ? 63 : pp);
    while (pp > 0 && t < pp * (129 - pp) / 2) --pp;
    while (pp < 63 && t >= (pp + 1) * (128 - pp) / 2) ++pp;
    p = pp;
    q = pp + (t - pp * (129 - pp) / 2);
}

__global__ __launch_bounds__(256, 3)
void simloss_kernel(const unsigned char* __restrict__ pk8,
                    float* __restrict__ part /* [NPIECE][NROWS] */) {
    __shared__ __attribute__((aligned(16))) unsigned char ldsB[32768];
    int wave = threadIdx.x >> 6;
    int lane = threadIdx.x & 63;
    int lr = lane & 15;                  // fragment col
    int lk = lane >> 4;                  // fragment row group
    int wr = wave >> 1, wc = wave & 1;
    // XCD-contiguous bijective swizzle: 2080 = 8 x 260
    int bt = (int)blockIdx.x;
    int t = (bt & 7) * 260 + (bt >> 3);
    int p, q;
    unrank_tile(t, p, q);

    const char* pkb = (const char*)pk8;

    // --- stage B panel q: contiguous 32 KB, 8 chunks of 1 KB per wave ---
#pragma unroll
    for (int i = 0; i < 8; ++i) {
        int chunk = wave * 8 + i;        // 0..31
        const char* src = pkb + (size_t)q * 32768 + (size_t)chunk * 1024
                        + (size_t)lane * 16;
        char* dst = (char*)ldsB + chunk * 1024;
        __builtin_amdgcn_global_load_lds((g_u32*)src, (l_u32*)dst, 16, 0, 0);
    }

    // --- A fragments into registers: 4 row-tiles x 8 slices (64 VGPR) ---
    const char* Abase = pkb + (size_t)(p * 8 + wr * 4) * 4096 + (size_t)lane * 8;
    long long Ar[4][8];
#pragma unroll
    for (int m = 0; m < 4; ++m)
#pragma unroll
        for (int s = 0; s < 8; ++s)
            Ar[m][s] = *(const long long*)(Abase + m * 4096 + s * 512);

    f32x4 acc[4][4];
#pragma unroll
    for (int m = 0; m < 4; ++m)
#pragma unroll
        for (int n = 0; n < 4; ++n) acc[m][n] = (f32x4){0.f, 0.f, 0.f, 0.f};

    __syncthreads();                     // waits vmcnt(0) + lgkmcnt(0)

    // --- K-loop: pure LDS reads + MFMA, no barriers ---
    const char* Bb = (const char*)ldsB + (size_t)(wc * 4) * 4096
                   + (size_t)lane * 8;
#pragma unroll
    for (int s = 0; s < 8; ++s) {
        long long Bf[4];
#pragma unroll
        for (int n = 0; n < 4; ++n)
            Bf[n] = *(const long long*)(Bb + n * 4096 + s * 512);
#pragma unroll
        for (int m = 0; m < 4; ++m)
#pragma unroll
            for (int n = 0; n < 4; ++n)
                acc[m][n] = __builtin_amdgcn_mfma_f32_16x16x32_fp8_fp8(
                    Ar[m][s], Bf[n], acc[m][n], 0, 0, 0);
    }

    // ---- epilogue (R12 verbatim): exp2, diag-zero, row + col sums ----
    int R0 = p * 128 + wr * 64;
    int C0 = q * 128 + wc * 64;
    float dacc[4][4];
#pragma unroll
    for (int m = 0; m < 4; ++m)
#pragma unroll
        for (int j = 0; j < 4; ++j) dacc[m][j] = 0.f;
    float cacc[4] = {0.f, 0.f, 0.f, 0.f};

#pragma unroll
    for (int m = 0; m < 4; ++m) {
        int gr = R0 + m * 16;
#pragma unroll
        for (int n = 0; n < 4; ++n) {
            int gc = C0 + n * 16;
            bool diagf = (gr == gc);      // uniform per fragment
            float cs_ = 0.f;
#pragma unroll
            for (int j = 0; j < 4; ++j) {
                float e = EXP2F(acc[m][n][j]);
                if (diagf && lr == lk * 4 + j) e = 0.0f;
                dacc[m][j] += e;
                cs_ += e;
            }
            cacc[n] += cs_;
        }
    }

    // row pieces: reduce over 16 col-lanes (lr); lanes lr==0 write (nt)
#pragma unroll
    for (int m = 0; m < 4; ++m)
#pragma unroll
        for (int j = 0; j < 4; ++j) {
            float v = dacc[m][j];
            v += __shfl_xor(v, 1);
            v += __shfl_xor(v, 2);
            v += __shfl_xor(v, 4);
            v += __shfl_xor(v, 8);
            if (lr == 0)
                __builtin_nontemporal_store(v,
                    &part[(size_t)(q * 2 + wc) * NROWS + R0 + m * 16 + lk * 4 + j]);
        }
    // col pieces: reduce over the 4 lk groups; lanes lk==0 (0..15) write (nt)
    if (p != q) {
#pragma unroll
        for (int n = 0; n < 4; ++n) {
            float c = cacc[n];
            c += __shfl_xor(c, 16);
            c += __shfl_xor(c, 32);
            if (lk == 0)
                __builtin_nontemporal_store(c,
                    &part[(size_t)(p * 2 + wr) * NROWS + C0 + n * 16 + lr]);
        }
    }
}

// ---------------------------------------------------------------------------
// Kernel C: per-row loss (plain stores, no atomics).
// One row per wave: den = sum of 128 pieces (lane gathers 2, shfl-reduce);
// cpart[r] = log(den) - rawdot*inv[r]*inv[r^B]*ln2.
// ---------------------------------------------------------------------------
__global__ void rowloss_kernel(const float* __restrict__ part,
                               const float* __restrict__ inv_arr,
                               const float* __restrict__ rawdot,
                               float* __restrict__ cpart /* [NROWS] */) {
    int wave = threadIdx.x >> 6;
    int lane = threadIdx.x & 63;
    int r = blockIdx.x * 4 + wave;
    float den = part[(size_t)lane * NROWS + r]
              + part[(size_t)(lane + 64) * NROWS + r];
#pragma unroll
    for (int m = 1; m < 64; m <<= 1) den += __shfl_xor(den, m);
    if (lane == 0) {
        float pdot = rawdot[r & (BATCH - 1)] * inv_arr[r] * inv_arr[r ^ BATCH];
        cpart[r] = logf(den) - pdot * LN2F;
    }
}

// ---------------------------------------------------------------------------
// Kernel D (R18 verbatim): final reduction of 8192 row losses -> loss / n
// ---------------------------------------------------------------------------
__global__ void final_kernel(const float* __restrict__ cpart,
                             float* __restrict__ out) {
    int lane = threadIdx.x & 63;
    int wave = threadIdx.x >> 6;
    double v = 0.0;
#pragma unroll
    for (int k = 0; k < 32; ++k)
        v += (double)cpart[threadIdx.x + k * 256];
#pragma unroll
    for (int m = 1; m < 64; m <<= 1) v += __shfl_xor(v, m);
    __shared__ double red[4];
    if (lane == 0) red[wave] = v;
    __syncthreads();
    if (threadIdx.x == 0)
        out[0] = (float)((red[0] + red[1] + red[2] + red[3]) / (double)NROWS);
}

// ---------------------------------------------------------------------------
extern "C" void kernel_launch(void* const* d_in, const int* in_sizes, int n_in,
                              void* d_out, int out_size, void* d_ws, size_t ws_size,
                              hipStream_t stream) {
    const float* z_i = (const float*)d_in[0];
    const float* z_j = (const float*)d_in[1];
    float* out = (float*)d_out;
    char* ws = (char*)d_ws;

    unsigned char* pk8 = (unsigned char*)ws;                               // 2 MB
    float* part   = (float*)(ws + (size_t)NROWS * DIM);                    // 4 MB
    float* inv_a  = (float*)(ws + (size_t)NROWS * DIM
                                + (size_t)NPIECE * NROWS * 4);             // 32 KB
    float* rawdot = inv_a + NROWS;                                         // 16 KB
    float* cpart  = rawdot + BATCH;                                        // 32 KB

    normalize_kernel<<<NROWS / 4, 256, 0, stream>>>(z_i, z_j, pk8, inv_a, rawdot);
    simloss_kernel<<<NBLK, 256, 0, stream>>>(pk8, part);
    rowloss_kernel<<<NROWS / 4, 256, 0, stream>>>(part, inv_a, rawdot, cpart);
    final_kernel<<<1, 256, 0, stream>>>(cpart, out);
}